// Round 4
// baseline (420.532 us; speedup 1.0000x reference)
//
#include <hip/hip_runtime.h>
#include <hip/hip_bf16.h>

#define NPTS 256
#define NB   4
#define KNN  27
#define EPSV 1e-5f

typedef unsigned short u16;
typedef __attribute__((ext_vector_type(8))) short bf16x8;
typedef __attribute__((ext_vector_type(4))) float f32x4;

// ---------------- workspace layout (bytes); ws_size ~256 MiB (poison fill) ----
#define OFF_IDX    0           // 4*256*27*4              = 110592
#define OFF_XYZH   131072      // 4*256*32*2              = 65536   bf16-hi [b][n][32]
#define OFF_XYZL   196608      // 65536                              bf16-lo
#define OFF_PQ     262144      // 4*6144*256*4            = 25165824 fp32 [b][M][n]
#define OFF_SLICE  25427968    // 4*6144*256*4            = 25165824 fp32 [b][2Co][n]
#define OFF_XCH    50593792    // 4*256*8160*2            = 16711680 bf16-hi [b][n][8160]
#define OFF_XCL    67305472    // 16711680                           bf16-lo
#define OFF_AH     84017152    // 6144*1536*2 max         = 18874368 bf16-hi A [Mpad][Kpad]
#define OFF_AL     102891520   // 18874368                           bf16-lo
#define OFF_Y      121765888   // 4*256*256*4             = 1048576
// total = 122814464 (~117 MiB)

__device__ __forceinline__ u16 bf16_rne(float a) {
    unsigned int u = __float_as_uint(a);
    return (u16)((u + 0x7fffu + ((u >> 16) & 1u)) >> 16);
}

// ---------------- kNN (+ xyz -> padded bf16 hi/lo [b][n][32]) ----------------
__device__ __forceinline__ float dist3_nocontract(float ax, float ay, float az,
                                                  float bx, float by, float bz) {
#pragma clang fp contract(off)
    float dx = bx - ax, dy = by - ay, dz = bz - az;
    float s = dx * dx;
    s = s + dy * dy;
    s = s + dz * dz;
    return s;
}

__global__ __launch_bounds__(64) void knn_kernel(const float* __restrict__ x,
                                                 int* __restrict__ idx,
                                                 u16* __restrict__ xyzH,
                                                 u16* __restrict__ xyzL) {
    int pt = blockIdx.x;            // 0..1023
    int b = pt >> 8, n = pt & 255;
    int lane = threadIdx.x;

    float xp0 = x[pt * 3 + 0];
    float xp1 = x[pt * 3 + 1];
    float xp2 = x[pt * 3 + 2];

    if (lane < 32) {
        float v = (lane < 3) ? x[pt * 3 + lane] : 0.f;
        u16 h = bf16_rne(v);
        float fh = __uint_as_float((unsigned int)h << 16);
        u16 l = bf16_rne(v - fh);
        long o = ((long)b * NPTS + n) * 32 + lane;
        xyzH[o] = h;
        xyzL[o] = l;
    }

    unsigned long long key[4];
#pragma unroll
    for (int u = 0; u < 4; ++u) {
        int j = lane + 64 * u;
        int gj = b * NPTS + j;
        float d = dist3_nocontract(xp0, xp1, xp2,
                                   x[gj * 3 + 0], x[gj * 3 + 1], x[gj * 3 + 2]);
        key[u] = ((unsigned long long)__float_as_uint(d) << 32) | (unsigned int)j;
    }

    for (int r = 0; r < KNN; ++r) {
        unsigned long long m = key[0];
        m = key[1] < m ? key[1] : m;
        m = key[2] < m ? key[2] : m;
        m = key[3] < m ? key[3] : m;
#pragma unroll
        for (int off = 32; off; off >>= 1) {
            unsigned long long o = __shfl_xor(m, off);
            m = o < m ? o : m;
        }
        if (lane == 0) idx[pt * KNN + r] = (int)(m & 0xffffffffu);
#pragma unroll
        for (int u = 0; u < 4; ++u)
            if (key[u] == m) key[u] = ~0ULL;
    }
}

// ---------------- weight prep: transform + bf16 hi/lo split (once) ----------
// mode 0: A[r][c] = r<Co ? w[r][c] : w[r-Co][K+c]-w[r-Co][c]  (w stride 2K)
// mode 1: A[r][c] = w[r][c] (stride K)
// Zero-fills c in [K,Kpad) and rows r in [M,Mpad). Grid: (Mpad, ceil(Kpad/2048)).
__global__ __launch_bounds__(256) void prep_a(const float* __restrict__ w,
                                              u16* __restrict__ Ah, u16* __restrict__ Al,
                                              int M, int Co, int K, int Kpad, int mode) {
    int r = blockIdx.x;
    int c0 = (blockIdx.y * 256 + threadIdx.x) * 8;
    if (c0 >= Kpad) return;
    float v[8];
#pragma unroll
    for (int j = 0; j < 8; ++j) {
        int c = c0 + j;
        float a = 0.f;
        if (c < K && r < M) {
            if (mode == 1) a = w[(long)r * K + c];
            else if (r < Co) a = w[(long)r * (2 * K) + c];
            else {
                long base = (long)(r - Co) * (2 * K);
                a = w[base + K + c] - w[base + c];
            }
        }
        v[j] = a;
    }
    bf16x8 hv, lv;
#pragma unroll
    for (int j = 0; j < 8; ++j) {
        u16 h = bf16_rne(v[j]);
        float fh = __uint_as_float((unsigned int)h << 16);
        u16 l = bf16_rne(v[j] - fh);
        hv[j] = (short)h;
        lv[j] = (short)l;
    }
    *(bf16x8*)&Ah[(long)r * Kpad + c0] = hv;
    *(bf16x8*)&Al[(long)r * Kpad + c0] = lv;
}

// ---------------- split-bf16 MFMA GEMM (no conversion in loop) --------------
// out[b][r][n] (+)= sum_c A[r][c]*F[b][n][c]; A,F prestored bf16 hi/lo.
// a*f ~= ah*fh + ah*fl + al*fh. Block 128x128, BK=32; 4 waves 2x2; wave 64x64
// = 4x4 tiles of (verified) mfma_f32_16x16x32_bf16.
__global__ __launch_bounds__(256) void gemm_mfma(
    const u16* __restrict__ Ah, const u16* __restrict__ Al,
    const u16* __restrict__ Bh, const u16* __restrict__ Bl,
    float* __restrict__ out, int M, int Kpad, int K,
    int ldF, long bsF, long bsO, int nsplit)
{
    __shared__ u16 sAh[128][40], sAl[128][40], sBh[128][40], sBl[128][40];

    int bz = blockIdx.z;
    int b = bz / nsplit, slice = bz - b * nsplit;
    int kchunk = (((K + nsplit - 1) / nsplit) + 31) & ~31;
    int kstart = slice * kchunk;
    int kend = K < kstart + kchunk ? K : kstart + kchunk;

    const u16* pBh = Bh + (long)b * bsF;
    const u16* pBl = Bl + (long)b * bsF;
    float* Ob = out + (long)b * bsO;

    int m0 = blockIdx.x * 128, n0 = blockIdx.y * 128;
    int tid = threadIdx.x, lane = tid & 63, wid = tid >> 6;
    int wm = (wid >> 1) * 64, wn = (wid & 1) * 64;
    int lrow = lane & 15, quad = lane >> 4;

    int srow = tid >> 1;            // 0..127
    int sk = (tid & 1) * 16;        // 0,16

    const u16* gAh = Ah + (long)(m0 + srow) * Kpad + sk;
    const u16* gAl = Al + (long)(m0 + srow) * Kpad + sk;
    const u16* gBh = pBh + (long)(n0 + srow) * ldF + sk;
    const u16* gBl = pBl + (long)(n0 + srow) * ldF + sk;

    f32x4 acc[4][4] = {};

    for (int kk = kstart; kk < kend; kk += 32) {
        bf16x8 a0 = *(const bf16x8*)(gAh + kk);
        bf16x8 a1 = *(const bf16x8*)(gAh + kk + 8);
        bf16x8 a2 = *(const bf16x8*)(gAl + kk);
        bf16x8 a3 = *(const bf16x8*)(gAl + kk + 8);
        bf16x8 b0 = *(const bf16x8*)(gBh + kk);
        bf16x8 b1 = *(const bf16x8*)(gBh + kk + 8);
        bf16x8 b2 = *(const bf16x8*)(gBl + kk);
        bf16x8 b3 = *(const bf16x8*)(gBl + kk + 8);

        __syncthreads();   // previous iteration's fragment reads complete

        *(bf16x8*)&sAh[srow][sk] = a0;
        *(bf16x8*)&sAh[srow][sk + 8] = a1;
        *(bf16x8*)&sAl[srow][sk] = a2;
        *(bf16x8*)&sAl[srow][sk + 8] = a3;
        *(bf16x8*)&sBh[srow][sk] = b0;
        *(bf16x8*)&sBh[srow][sk + 8] = b1;
        *(bf16x8*)&sBl[srow][sk] = b2;
        *(bf16x8*)&sBl[srow][sk + 8] = b3;

        __syncthreads();

        bf16x8 fbh[4], fbl[4];
#pragma unroll
        for (int nt = 0; nt < 4; ++nt) {
            fbh[nt] = *(const bf16x8*)&sBh[wn + nt * 16 + lrow][quad * 8];
            fbl[nt] = *(const bf16x8*)&sBl[wn + nt * 16 + lrow][quad * 8];
        }
#pragma unroll
        for (int mt = 0; mt < 4; ++mt) {
            bf16x8 fah = *(const bf16x8*)&sAh[wm + mt * 16 + lrow][quad * 8];
            bf16x8 fal = *(const bf16x8*)&sAl[wm + mt * 16 + lrow][quad * 8];
#pragma unroll
            for (int nt = 0; nt < 4; ++nt) {
                acc[mt][nt] = __builtin_amdgcn_mfma_f32_16x16x32_bf16(fah, fbh[nt], acc[mt][nt], 0, 0, 0);
                acc[mt][nt] = __builtin_amdgcn_mfma_f32_16x16x32_bf16(fah, fbl[nt], acc[mt][nt], 0, 0, 0);
                acc[mt][nt] = __builtin_amdgcn_mfma_f32_16x16x32_bf16(fal, fbh[nt], acc[mt][nt], 0, 0, 0);
            }
        }
    }

    // epilogue: C/D layout col=lane&15, row=quad*4+reg  [m89-verified]
#pragma unroll
    for (int mt = 0; mt < 4; ++mt)
#pragma unroll
        for (int nt = 0; nt < 4; ++nt) {
            int C = n0 + wn + nt * 16 + lrow;
            int Rb = m0 + wm + mt * 16 + quad * 4;
#pragma unroll
            for (int r = 0; r < 4; ++r) {
                int R = Rb + r;
                if (R < M) {
                    float* po = Ob + (long)R * NPTS + C;
                    if (nsplit == 1) *po = acc[mt][nt][r];
                    else atomicAdd(po, acc[mt][nt][r]);
                }
            }
        }
}

// ---------------- fused neighbor gather + stats + BN/lrelu + tp concat -------
__global__ __launch_bounds__(256) void gather_finalize(
    const float* __restrict__ PQ, const int* __restrict__ idx,
    const float* __restrict__ g, const float* __restrict__ beta,
    float* __restrict__ slice, int Co)
{
    __shared__ float p_sh[NB][NPTS];
    __shared__ float val_sh[NB][NPTS];
    __shared__ float red[8];
    int o = blockIdx.x;
    int b = threadIdx.x >> 6;
    int lane = threadIdx.x & 63;

    const float* Prow = PQ + ((long)b * 2 * Co + o) * NPTS;
    const float* Qrow = PQ + ((long)b * 2 * Co + Co + o) * NPTS;

#pragma unroll
    for (int u = 0; u < 4; ++u) p_sh[b][lane + 64 * u] = Prow[lane + 64 * u];
    __syncthreads();

    float mx[4], mn[4];
    float s = 0.f, ss = 0.f;
#pragma unroll
    for (int u = 0; u < 4; ++u) {
        int n = lane + 64 * u;
        float q = Qrow[n];
        const int* ip = idx + ((long)b * NPTS + n) * KNN;
        float vmx = -__builtin_inff(), vmn = __builtin_inff();
#pragma unroll
        for (int k = 0; k < KNN; ++k) {
            float h = p_sh[b][ip[k]] + q;
            s += h;
            ss += h * h;
            vmx = fmaxf(vmx, h);
            vmn = fminf(vmn, h);
        }
        mx[u] = vmx;
        mn[u] = vmn;
    }
#pragma unroll
    for (int off = 32; off; off >>= 1) {
        s += __shfl_xor(s, off);
        ss += __shfl_xor(ss, off);
    }
    if (lane == 0) { red[b] = s; red[4 + b] = ss; }
    __syncthreads();

    float ts = (red[0] + red[1]) + (red[2] + red[3]);
    float tss = (red[4] + red[5]) + (red[6] + red[7]);
    const float cnt = (float)(NB * NPTS * KNN);
    float mean = ts / cnt;
    float var = tss / cnt - mean * mean;
    float sc = g[o] * (1.0f / sqrtf(var + EPSV));
    float tt = beta[o] - mean * sc;

#pragma unroll
    for (int u = 0; u < 4; ++u) {
        int n = lane + 64 * u;
        float v = (sc >= 0.f) ? mx[u] : mn[u];
        float z = sc * v + tt;
        val_sh[b][n] = z >= 0.f ? z : 0.2f * z;
    }
    __syncthreads();

#pragma unroll
    for (int u = 0; u < 4; ++u) {
        int n = lane + 64 * u;
        float tp = 0.5f * (val_sh[0][n] + val_sh[1][n]);
        slice[((long)b * 2 * Co + o) * NPTS + n] = val_sh[b][n];
        slice[((long)b * 2 * Co + Co + o) * NPTS + n] = tp;
    }
}

// ---------------- transpose [b][C][n] -> bf16 hi/lo [b][n][8160] at offc ----
__global__ __launch_bounds__(256) void transpose_cn(
    const float* __restrict__ slice, u16* __restrict__ xH, u16* __restrict__ xL,
    int Ctot, int offc)
{
    __shared__ float t[32][33];
    int c0 = blockIdx.x * 32, n0 = blockIdx.y * 32, b = blockIdx.z;
    const float* S = slice + (long)b * Ctot * NPTS;
    int tid = threadIdx.x;
    int r = tid >> 3, s4 = (tid & 7) * 4;

    f32x4 v = *(const f32x4*)&S[(long)(c0 + r) * NPTS + n0 + s4];
    t[r][s4 + 0] = v[0];
    t[r][s4 + 1] = v[1];
    t[r][s4 + 2] = v[2];
    t[r][s4 + 3] = v[3];
    __syncthreads();

    long base = ((long)b * NPTS + n0 + r) * 8160 + offc + c0 + s4;
    typedef __attribute__((ext_vector_type(4))) unsigned short u16x4;
    u16x4 hv, lv;
#pragma unroll
    for (int j = 0; j < 4; ++j) {
        float a = t[s4 + j][r];
        u16 h = bf16_rne(a);
        float fh = __uint_as_float((unsigned int)h << 16);
        hv[j] = h;
        lv[j] = bf16_rne(a - fh);
    }
    *(u16x4*)&xH[base] = hv;
    *(u16x4*)&xL[base] = lv;
}

// ---------------- final BN + lrelu -> fp32 out ----------------
__global__ __launch_bounds__(256) void final_bn(const float* __restrict__ y,
                                                const float* __restrict__ g4,
                                                const float* __restrict__ b4,
                                                float* __restrict__ out) {
    __shared__ float red[8];
    int o = blockIdx.x;
    int tid = threadIdx.x;
    int lane = tid & 63, w = tid >> 6;

    float v[4];
    float s = 0.f, ss = 0.f;
#pragma unroll
    for (int b = 0; b < 4; ++b) {
        v[b] = y[(long)b * 65536 + o * 256 + tid];
        s += v[b];
        ss += v[b] * v[b];
    }
#pragma unroll
    for (int off = 32; off; off >>= 1) {
        s += __shfl_xor(s, off);
        ss += __shfl_xor(ss, off);
    }
    if (lane == 0) { red[w] = s; red[4 + w] = ss; }
    __syncthreads();
    s = (red[0] + red[1]) + (red[2] + red[3]);
    ss = (red[4] + red[5]) + (red[6] + red[7]);
    float mean = s / 1024.f;
    float var = ss / 1024.f - mean * mean;
    float sc = g4[o] * (1.0f / sqrtf(var + EPSV));
    float tt = b4[o] - mean * sc;
#pragma unroll
    for (int b = 0; b < 4; ++b) {
        float z = sc * v[b] + tt;
        z = z >= 0.f ? z : 0.2f * z;
        out[(long)b * 65536 + o * 256 + tid] = z;
    }
}

// ---------------- launch ----------------
extern "C" void kernel_launch(void* const* d_in, const int* in_sizes, int n_in,
                              void* d_out, int out_size, void* d_ws, size_t ws_size,
                              hipStream_t stream) {
    const float* x = (const float*)d_in[0];
    const float* wl[4];
    const float* gl[4];
    const float* bl[4];
    for (int i = 0; i < 4; ++i) {
        wl[i] = (const float*)d_in[1 + 3 * i];
        gl[i] = (const float*)d_in[2 + 3 * i];
        bl[i] = (const float*)d_in[3 + 3 * i];
    }
    const float* w4 = (const float*)d_in[13];
    const float* g4 = (const float*)d_in[14];
    const float* b4 = (const float*)d_in[15];

    char* ws = (char*)d_ws;
    int* idx = (int*)(ws + OFF_IDX);
    u16* xyzH = (u16*)(ws + OFF_XYZH);
    u16* xyzL = (u16*)(ws + OFF_XYZL);
    float* PQ = (float*)(ws + OFF_PQ);
    float* slice = (float*)(ws + OFF_SLICE);
    u16* xcH = (u16*)(ws + OFF_XCH);
    u16* xcL = (u16*)(ws + OFF_XCL);
    u16* Ah = (u16*)(ws + OFF_AH);
    u16* Al = (u16*)(ws + OFF_AL);
    float* y = (float*)(ws + OFF_Y);

    knn_kernel<<<dim3(NB * NPTS), dim3(64), 0, stream>>>(x, idx, xyzH, xyzL);

    const int Cf[4] = {3, 96, 384, 1536};
    const int Kp[4] = {32, 96, 384, 1536};    // K padded to 32
    const int Co[4] = {48, 192, 768, 3072};
    const int offc[4] = {0, 96, 480, 2016};
    const int inoff[4] = {0, 0, 96, 480};

    for (int i = 0; i < 4; ++i) {
        int M = 2 * Co[i];
        int Mpad = (M + 127) & ~127;
        int Kpad = Kp[i];
        // weight transform + split (once per layer)
        prep_a<<<dim3(Mpad, (Kpad + 2047) / 2048), dim3(256), 0, stream>>>(
            wl[i], Ah, Al, M, Co[i], Cf[i], Kpad, 0);

        const u16* BhP;
        const u16* BlP;
        int ldF;
        long bsF;
        if (i == 0) {
            BhP = xyzH; BlP = xyzL; ldF = 32; bsF = (long)NPTS * 32;
        } else {
            BhP = xcH + inoff[i]; BlP = xcL + inoff[i]; ldF = 8160; bsF = (long)NPTS * 8160;
        }
        int Keff = (i == 0) ? 32 : Cf[i];
        gemm_mfma<<<dim3(Mpad / 128, NPTS / 128, NB), dim3(256), 0, stream>>>(
            Ah, Al, BhP, BlP, PQ, M, Kpad, Keff, ldF, bsF, (long)M * NPTS, 1);

        gather_finalize<<<dim3(Co[i]), dim3(256), 0, stream>>>(PQ, idx, gl[i], bl[i],
                                                               slice, Co[i]);
        transpose_cn<<<dim3(M / 32, NPTS / 32, NB), dim3(256), 0, stream>>>(
            slice, xcH, xcL, M, offc[i]);
    }

    // final projection: prep w4, then split-K=8 atomic GEMM into zeroed y
    prep_a<<<dim3(256, 4), dim3(256), 0, stream>>>(w4, Ah, Al, 256, 0, 8160, 8192, 1);
    hipMemsetAsync(y, 0, (size_t)NB * 256 * 256 * 4, stream);
    gemm_mfma<<<dim3(2, 2, NB * 8), dim3(256), 0, stream>>>(
        Ah, Al, xcH, xcL, y, 256, 8192, 8160, 8160, (long)NPTS * 8160,
        (long)256 * NPTS, 8);
    final_bn<<<dim3(256), dim3(256), 0, stream>>>(y, g4, b4, (float*)d_out);
}

// Round 5
// 401.183 us; speedup vs baseline: 1.0482x; 1.0482x over previous
//
#include <hip/hip_runtime.h>
#include <hip/hip_bf16.h>

#define NPTS 256
#define NB   4
#define KNN  27
#define EPSV 1e-5f

typedef unsigned short u16;
typedef __attribute__((ext_vector_type(8))) short bf16x8;
typedef __attribute__((ext_vector_type(4))) float f32x4;

// ---------------- workspace layout (bytes); ws = 256 MiB ----------------
#define OFF_IDX    0           // 110592
#define OFF_XYZH   131072      // 65536   u16 [b][n][32]
#define OFF_XYZL   196608      // 65536
#define OFF_AH0    262144      // 128*32*2    = 8192
#define OFF_AL0    270336
#define OFF_AH1    278528      // 384*96*2    = 73728
#define OFF_AL1    352256
#define OFF_AH2    425984      // 1536*384*2  = 1179648
#define OFF_AL2    1605632
#define OFF_AH3    2785280     // 6144*1536*2 = 18874368
#define OFF_AL3    21659648
#define OFF_AH4    40534016    // 256*8160*2  = 4177920
#define OFF_AL4    44711936
#define OFF_PQ     48889856    // 3 * 4*6144*256*4 = 75497472 (partial planes)
#define OFF_SLICE  124387328   // 4*6144*256*4     = 25165824
#define OFF_XCH    149553152   // 4*256*8160*2     = 16711680
#define OFF_XCL    166264832   // 16711680
#define OFF_Y      182976512   // 8 * 4*256*256*4  = 8388608
// end 191365120 (~182.5 MiB)

__device__ __forceinline__ u16 bf16_rne(float a) {
    unsigned int u = __float_as_uint(a);
    return (u16)((u + 0x7fffu + ((u >> 16) & 1u)) >> 16);
}

// ---------------- kNN (+ xyz -> padded bf16 hi/lo [b][n][32]) ----------------
__device__ __forceinline__ float dist3_nocontract(float ax, float ay, float az,
                                                  float bx, float by, float bz) {
#pragma clang fp contract(off)
    float dx = bx - ax, dy = by - ay, dz = bz - az;
    float s = dx * dx;
    s = s + dy * dy;
    s = s + dz * dz;
    return s;
}

__global__ __launch_bounds__(64) void knn_kernel(const float* __restrict__ x,
                                                 int* __restrict__ idx,
                                                 u16* __restrict__ xyzH,
                                                 u16* __restrict__ xyzL) {
    int pt = blockIdx.x;            // 0..1023
    int b = pt >> 8, n = pt & 255;
    int lane = threadIdx.x;

    float xp0 = x[pt * 3 + 0];
    float xp1 = x[pt * 3 + 1];
    float xp2 = x[pt * 3 + 2];

    if (lane < 32) {
        float v = (lane < 3) ? x[pt * 3 + lane] : 0.f;
        u16 h = bf16_rne(v);
        float fh = __uint_as_float((unsigned int)h << 16);
        u16 l = bf16_rne(v - fh);
        long o = ((long)b * NPTS + n) * 32 + lane;
        xyzH[o] = h;
        xyzL[o] = l;
    }

    unsigned long long key[4];
#pragma unroll
    for (int u = 0; u < 4; ++u) {
        int j = lane + 64 * u;
        int gj = b * NPTS + j;
        float d = dist3_nocontract(xp0, xp1, xp2,
                                   x[gj * 3 + 0], x[gj * 3 + 1], x[gj * 3 + 2]);
        key[u] = ((unsigned long long)__float_as_uint(d) << 32) | (unsigned int)j;
    }

    for (int r = 0; r < KNN; ++r) {
        unsigned long long m = key[0];
        m = key[1] < m ? key[1] : m;
        m = key[2] < m ? key[2] : m;
        m = key[3] < m ? key[3] : m;
#pragma unroll
        for (int off = 32; off; off >>= 1) {
            unsigned long long o = __shfl_xor(m, off);
            m = o < m ? o : m;
        }
        if (lane == 0) idx[pt * KNN + r] = (int)(m & 0xffffffffu);
#pragma unroll
        for (int u = 0; u < 4; ++u)
            if (key[u] == m) key[u] = ~0ULL;
    }
}

// ---------------- consolidated weight prep (all 5 matrices, one dispatch) ----
// job j: A[r][c] = (mode0) r<Co ? w[r][c] : w[r-Co][K+c]-w[r-Co][c]  (stride 2K)
//        (mode1) w[r][c] (stride K);  zero-fill r in [M,Mpad), c in [K,Kpad).
__global__ __launch_bounds__(256) void prep_all(
    const float* __restrict__ w0, const float* __restrict__ w1,
    const float* __restrict__ w2, const float* __restrict__ w3,
    const float* __restrict__ w4, char* __restrict__ ws)
{
    // cumulative block counts: 128, 512, 2048, 8192, 9216
    int bid = blockIdx.x;
    const float* w;
    int r, cbase = 0, M, Co, K, Kpad, mode;
    long offH, offL;
    if (bid < 128)      { w = w0; r = bid;        M = 96;   Co = 48;   K = 3;    Kpad = 32;   mode = 0; offH = OFF_AH0; offL = OFF_AL0; }
    else if (bid < 512) { w = w1; r = bid - 128;  M = 384;  Co = 192;  K = 96;   Kpad = 96;   mode = 0; offH = OFF_AH1; offL = OFF_AL1; }
    else if (bid < 2048){ w = w2; r = bid - 512;  M = 1536; Co = 768;  K = 384;  Kpad = 384;  mode = 0; offH = OFF_AH2; offL = OFF_AL2; }
    else if (bid < 8192){ w = w3; r = bid - 2048; M = 6144; Co = 3072; K = 1536; Kpad = 1536; mode = 0; offH = OFF_AH3; offL = OFF_AL3; }
    else { int loc = bid - 8192; w = w4; r = loc >> 2; cbase = (loc & 3) * 2048;
           M = 256; Co = 0; K = 8160; Kpad = 8160; mode = 1; offH = OFF_AH4; offL = OFF_AL4; }

    int c0 = cbase + threadIdx.x * 8;
    if (c0 >= Kpad) return;
    u16* Ah = (u16*)(ws + offH);
    u16* Al = (u16*)(ws + offL);

    float v[8];
#pragma unroll
    for (int j = 0; j < 8; ++j) {
        int c = c0 + j;
        float a = 0.f;
        if (c < K && r < M) {
            if (mode == 1) a = w[(long)r * K + c];
            else if (r < Co) a = w[(long)r * (2 * K) + c];
            else {
                long base = (long)(r - Co) * (2 * K);
                a = w[base + K + c] - w[base + c];
            }
        }
        v[j] = a;
    }
    bf16x8 hv, lv;
#pragma unroll
    for (int j = 0; j < 8; ++j) {
        u16 h = bf16_rne(v[j]);
        float fh = __uint_as_float((unsigned int)h << 16);
        hv[j] = (short)h;
        lv[j] = (short)bf16_rne(v[j] - fh);
    }
    *(bf16x8*)&Ah[(long)r * Kpad + c0] = hv;
    *(bf16x8*)&Al[(long)r * Kpad + c0] = lv;
}

// ---------------- split-bf16 MFMA GEMM, split-K into private partial planes --
// plane s: out[s*pstride + b*bsO + r*256 + n] = sum_{c in slice s} A[r][c]*F[b][n][c]
// a*f ~= ah*fh + ah*fl + al*fh. Block 128x128, BK=32; 4 waves 2x2; wave 64x64
// = 4x4 tiles of (verified) mfma_f32_16x16x32_bf16. All K-slices are
// multiples of 32 -> no bounds checks in the hot loop.
__global__ __launch_bounds__(256) void gemm_mfma(
    const u16* __restrict__ Ah, const u16* __restrict__ Al,
    const u16* __restrict__ Bh, const u16* __restrict__ Bl,
    float* __restrict__ out, int M, int Kpad, int K,
    int ldF, long bsF, long bsO, int nsplit, long pstride)
{
    __shared__ u16 sAh[128][40], sAl[128][40], sBh[128][40], sBl[128][40];

    int bz = blockIdx.z;
    int b = bz / nsplit, slice = bz - b * nsplit;
    int kchunk = (((K + nsplit - 1) / nsplit) + 31) & ~31;
    int kstart = slice * kchunk;
    int kend = K < kstart + kchunk ? K : kstart + kchunk;

    const u16* pBh = Bh + (long)b * bsF;
    const u16* pBl = Bl + (long)b * bsF;
    float* Ob = out + (long)slice * pstride + (long)b * bsO;

    int m0 = blockIdx.x * 128, n0 = blockIdx.y * 128;
    int tid = threadIdx.x, lane = tid & 63, wid = tid >> 6;
    int wm = (wid >> 1) * 64, wn = (wid & 1) * 64;
    int lrow = lane & 15, quad = lane >> 4;

    int srow = tid >> 1;            // 0..127
    int sk = (tid & 1) * 16;        // 0,16

    const u16* gAh = Ah + (long)(m0 + srow) * Kpad + sk;
    const u16* gAl = Al + (long)(m0 + srow) * Kpad + sk;
    const u16* gBh = pBh + (long)(n0 + srow) * ldF + sk;
    const u16* gBl = pBl + (long)(n0 + srow) * ldF + sk;

    f32x4 acc[4][4] = {};

    for (int kk = kstart; kk < kend; kk += 32) {
        bf16x8 a0 = *(const bf16x8*)(gAh + kk);
        bf16x8 a1 = *(const bf16x8*)(gAh + kk + 8);
        bf16x8 a2 = *(const bf16x8*)(gAl + kk);
        bf16x8 a3 = *(const bf16x8*)(gAl + kk + 8);
        bf16x8 b0 = *(const bf16x8*)(gBh + kk);
        bf16x8 b1 = *(const bf16x8*)(gBh + kk + 8);
        bf16x8 b2 = *(const bf16x8*)(gBl + kk);
        bf16x8 b3 = *(const bf16x8*)(gBl + kk + 8);

        __syncthreads();   // previous iteration's fragment reads complete

        *(bf16x8*)&sAh[srow][sk] = a0;
        *(bf16x8*)&sAh[srow][sk + 8] = a1;
        *(bf16x8*)&sAl[srow][sk] = a2;
        *(bf16x8*)&sAl[srow][sk + 8] = a3;
        *(bf16x8*)&sBh[srow][sk] = b0;
        *(bf16x8*)&sBh[srow][sk + 8] = b1;
        *(bf16x8*)&sBl[srow][sk] = b2;
        *(bf16x8*)&sBl[srow][sk + 8] = b3;

        __syncthreads();

        bf16x8 fbh[4], fbl[4];
#pragma unroll
        for (int nt = 0; nt < 4; ++nt) {
            fbh[nt] = *(const bf16x8*)&sBh[wn + nt * 16 + lrow][quad * 8];
            fbl[nt] = *(const bf16x8*)&sBl[wn + nt * 16 + lrow][quad * 8];
        }
#pragma unroll
        for (int mt = 0; mt < 4; ++mt) {
            bf16x8 fah = *(const bf16x8*)&sAh[wm + mt * 16 + lrow][quad * 8];
            bf16x8 fal = *(const bf16x8*)&sAl[wm + mt * 16 + lrow][quad * 8];
#pragma unroll
            for (int nt = 0; nt < 4; ++nt) {
                acc[mt][nt] = __builtin_amdgcn_mfma_f32_16x16x32_bf16(fah, fbh[nt], acc[mt][nt], 0, 0, 0);
                acc[mt][nt] = __builtin_amdgcn_mfma_f32_16x16x32_bf16(fah, fbl[nt], acc[mt][nt], 0, 0, 0);
                acc[mt][nt] = __builtin_amdgcn_mfma_f32_16x16x32_bf16(fal, fbh[nt], acc[mt][nt], 0, 0, 0);
            }
        }
    }

    // epilogue: C/D layout col=lane&15, row=quad*4+reg  [m89-verified]
#pragma unroll
    for (int mt = 0; mt < 4; ++mt)
#pragma unroll
        for (int nt = 0; nt < 4; ++nt) {
            int C = n0 + wn + nt * 16 + lrow;
            int Rb = m0 + wm + mt * 16 + quad * 4;
#pragma unroll
            for (int r = 0; r < 4; ++r) {
                int R = Rb + r;
                if (R < M) Ob[(long)R * NPTS + C] = acc[mt][nt][r];
            }
        }
}

// ---------------- fused gather + stats + BN/lrelu + tp concat ---------------
// Sums nsplit partial planes when reading P/Q.
__global__ __launch_bounds__(256) void gather_finalize(
    const float* __restrict__ PQ, long pstride, int nsplit,
    const int* __restrict__ idx,
    const float* __restrict__ g, const float* __restrict__ beta,
    float* __restrict__ slice, int Co)
{
    __shared__ float p_sh[NB][NPTS];
    __shared__ float val_sh[NB][NPTS];
    __shared__ float red[8];
    int o = blockIdx.x;
    int b = threadIdx.x >> 6;
    int lane = threadIdx.x & 63;

    long ip0 = ((long)b * 2 * Co + o) * NPTS;
    long iq0 = ((long)b * 2 * Co + Co + o) * NPTS;

#pragma unroll
    for (int u = 0; u < 4; ++u) {
        int n = lane + 64 * u;
        float v = 0.f;
        for (int s = 0; s < nsplit; ++s) v += PQ[s * pstride + ip0 + n];
        p_sh[b][n] = v;
    }
    __syncthreads();

    float mx[4], mn[4];
    float s = 0.f, ss = 0.f;
#pragma unroll
    for (int u = 0; u < 4; ++u) {
        int n = lane + 64 * u;
        float q = 0.f;
        for (int sp = 0; sp < nsplit; ++sp) q += PQ[sp * pstride + iq0 + n];
        const int* ip = idx + ((long)b * NPTS + n) * KNN;
        float vmx = -__builtin_inff(), vmn = __builtin_inff();
#pragma unroll
        for (int k = 0; k < KNN; ++k) {
            float h = p_sh[b][ip[k]] + q;
            s += h;
            ss += h * h;
            vmx = fmaxf(vmx, h);
            vmn = fminf(vmn, h);
        }
        mx[u] = vmx;
        mn[u] = vmn;
    }
#pragma unroll
    for (int off = 32; off; off >>= 1) {
        s += __shfl_xor(s, off);
        ss += __shfl_xor(ss, off);
    }
    if (lane == 0) { red[b] = s; red[4 + b] = ss; }
    __syncthreads();

    float ts = (red[0] + red[1]) + (red[2] + red[3]);
    float tss = (red[4] + red[5]) + (red[6] + red[7]);
    const float cnt = (float)(NB * NPTS * KNN);
    float mean = ts / cnt;
    float var = tss / cnt - mean * mean;
    float sc = g[o] * (1.0f / sqrtf(var + EPSV));
    float tt = beta[o] - mean * sc;

#pragma unroll
    for (int u = 0; u < 4; ++u) {
        int n = lane + 64 * u;
        float v = (sc >= 0.f) ? mx[u] : mn[u];
        float z = sc * v + tt;
        val_sh[b][n] = z >= 0.f ? z : 0.2f * z;
    }
    __syncthreads();

#pragma unroll
    for (int u = 0; u < 4; ++u) {
        int n = lane + 64 * u;
        float tp = 0.5f * (val_sh[0][n] + val_sh[1][n]);
        slice[((long)b * 2 * Co + o) * NPTS + n] = val_sh[b][n];
        slice[((long)b * 2 * Co + Co + o) * NPTS + n] = tp;
    }
}

// ---------------- transpose [b][C][n] -> bf16 hi/lo [b][n][8160] at offc ----
__global__ __launch_bounds__(256) void transpose_cn(
    const float* __restrict__ slice, u16* __restrict__ xH, u16* __restrict__ xL,
    int Ctot, int offc)
{
    __shared__ float t[32][33];
    int c0 = blockIdx.x * 32, n0 = blockIdx.y * 32, b = blockIdx.z;
    const float* S = slice + (long)b * Ctot * NPTS;
    int tid = threadIdx.x;
    int r = tid >> 3, s4 = (tid & 7) * 4;

    f32x4 v = *(const f32x4*)&S[(long)(c0 + r) * NPTS + n0 + s4];
    t[r][s4 + 0] = v[0];
    t[r][s4 + 1] = v[1];
    t[r][s4 + 2] = v[2];
    t[r][s4 + 3] = v[3];
    __syncthreads();

    long base = ((long)b * NPTS + n0 + r) * 8160 + offc + c0 + s4;
    typedef __attribute__((ext_vector_type(4))) unsigned short u16x4;
    u16x4 hv, lv;
#pragma unroll
    for (int j = 0; j < 4; ++j) {
        float a = t[s4 + j][r];
        u16 h = bf16_rne(a);
        float fh = __uint_as_float((unsigned int)h << 16);
        hv[j] = h;
        lv[j] = bf16_rne(a - fh);
    }
    *(u16x4*)&xH[base] = hv;
    *(u16x4*)&xL[base] = lv;
}

// ---------------- final BN + lrelu -> fp32 out (sums 8 partial y planes) ----
__global__ __launch_bounds__(256) void final_bn(const float* __restrict__ y,
                                                const float* __restrict__ g4,
                                                const float* __restrict__ b4,
                                                float* __restrict__ out) {
    __shared__ float red[8];
    int o = blockIdx.x;
    int tid = threadIdx.x;
    int lane = tid & 63, w = tid >> 6;

    float v[4];
    float s = 0.f, ss = 0.f;
#pragma unroll
    for (int b = 0; b < 4; ++b) {
        float acc = 0.f;
#pragma unroll
        for (int sp = 0; sp < 8; ++sp)
            acc += y[sp * 262144 + b * 65536 + o * 256 + tid];
        v[b] = acc;
        s += acc;
        ss += acc * acc;
    }
#pragma unroll
    for (int off = 32; off; off >>= 1) {
        s += __shfl_xor(s, off);
        ss += __shfl_xor(ss, off);
    }
    if (lane == 0) { red[w] = s; red[4 + w] = ss; }
    __syncthreads();
    s = (red[0] + red[1]) + (red[2] + red[3]);
    ss = (red[4] + red[5]) + (red[6] + red[7]);
    float mean = s / 1024.f;
    float var = ss / 1024.f - mean * mean;
    float sc = g4[o] * (1.0f / sqrtf(var + EPSV));
    float tt = b4[o] - mean * sc;
#pragma unroll
    for (int b = 0; b < 4; ++b) {
        float z = sc * v[b] + tt;
        z = z >= 0.f ? z : 0.2f * z;
        out[(long)b * 65536 + o * 256 + tid] = z;
    }
}

// ---------------- launch ----------------
extern "C" void kernel_launch(void* const* d_in, const int* in_sizes, int n_in,
                              void* d_out, int out_size, void* d_ws, size_t ws_size,
                              hipStream_t stream) {
    const float* x = (const float*)d_in[0];
    const float* wl[4];
    const float* gl[4];
    const float* bl[4];
    for (int i = 0; i < 4; ++i) {
        wl[i] = (const float*)d_in[1 + 3 * i];
        gl[i] = (const float*)d_in[2 + 3 * i];
        bl[i] = (const float*)d_in[3 + 3 * i];
    }
    const float* w4 = (const float*)d_in[13];
    const float* g4 = (const float*)d_in[14];
    const float* b4 = (const float*)d_in[15];

    char* ws = (char*)d_ws;
    int* idx = (int*)(ws + OFF_IDX);
    u16* xyzH = (u16*)(ws + OFF_XYZH);
    u16* xyzL = (u16*)(ws + OFF_XYZL);
    float* PQ = (float*)(ws + OFF_PQ);
    float* slice = (float*)(ws + OFF_SLICE);
    u16* xcH = (u16*)(ws + OFF_XCH);
    u16* xcL = (u16*)(ws + OFF_XCL);
    float* y = (float*)(ws + OFF_Y);

    knn_kernel<<<dim3(NB * NPTS), dim3(64), 0, stream>>>(x, idx, xyzH, xyzL);
    prep_all<<<dim3(9216), dim3(256), 0, stream>>>(wl[0], wl[1], wl[2], wl[3], w4, ws);

    const int Kp[4] = {32, 96, 384, 1536};     // padded K (multiples of 32)
    const int Co[4] = {48, 192, 768, 3072};
    const int offc[4] = {0, 96, 480, 2016};
    const int inoff[4] = {0, 0, 96, 480};
    const int nsp[4] = {1, 3, 2, 3};
    const long aoffH[4] = {OFF_AH0, OFF_AH1, OFF_AH2, OFF_AH3};
    const long aoffL[4] = {OFF_AL0, OFF_AL1, OFF_AL2, OFF_AL3};

    for (int i = 0; i < 4; ++i) {
        int M = 2 * Co[i];
        int Mpad = (M + 127) & ~127;
        const u16* Ah = (const u16*)(ws + aoffH[i]);
        const u16* Al = (const u16*)(ws + aoffL[i]);

        const u16* BhP;
        const u16* BlP;
        int ldF;
        long bsF;
        if (i == 0) { BhP = xyzH; BlP = xyzL; ldF = 32; bsF = (long)NPTS * 32; }
        else { BhP = xcH + inoff[i]; BlP = xcL + inoff[i]; ldF = 8160; bsF = (long)NPTS * 8160; }

        long pstride = (long)NB * M * NPTS;   // one partial plane
        gemm_mfma<<<dim3(Mpad / 128, NPTS / 128, NB * nsp[i]), dim3(256), 0, stream>>>(
            Ah, Al, BhP, BlP, PQ, M, Kp[i], Kp[i], ldF, bsF, (long)M * NPTS,
            nsp[i], pstride);

        gather_finalize<<<dim3(Co[i]), dim3(256), 0, stream>>>(
            PQ, pstride, nsp[i], idx, gl[i], bl[i], slice, Co[i]);
        transpose_cn<<<dim3(M / 32, NPTS / 32, NB), dim3(256), 0, stream>>>(
            slice, xcH, xcL, M, offc[i]);
    }

    // final projection: split-K=8 into 8 private y planes, summed in final_bn
    gemm_mfma<<<dim3(2, 2, NB * 8), dim3(256), 0, stream>>>(
        (const u16*)(ws + OFF_AH4), (const u16*)(ws + OFF_AL4), xcH, xcL, y,
        256, 8160, 8160, 8160, (long)NPTS * 8160, (long)256 * NPTS, 8,
        (long)NB * 256 * NPTS);
    final_bn<<<dim3(256), dim3(256), 0, stream>>>(y, g4, b4, (float*)d_out);
}

// Round 6
// 329.867 us; speedup vs baseline: 1.2749x; 1.2162x over previous
//
#include <hip/hip_runtime.h>
#include <hip/hip_bf16.h>

#define NPTS 256
#define NB   4
#define KNN  27
#define EPSV 1e-5f

typedef unsigned short u16;
typedef _Float16 f16;
typedef __attribute__((ext_vector_type(8))) _Float16 f16x8;
typedef __attribute__((ext_vector_type(4))) float f32x4;

// ---------------- workspace layout (bytes); ws = 256 MiB ----------------
#define OFF_IDX    0           // 110592
#define OFF_XYZ    131072      // 4*256*32*2 = 65536   f16 [b][n][32]
#define OFF_A0     262144      // 128*32*2    = 8192
#define OFF_A1     270336      // 384*96*2    = 73728
#define OFF_A2     344064      // 1536*384*2  = 1179648
#define OFF_A3     1523712     // 6144*1536*2 = 18874368
#define OFF_A4     20398080    // 256*8160*2  = 4177920
#define OFF_PQ     24576000    // up to 2*4*6144*256*4 = 50331648 partial planes
#define OFF_SLICE  74907648    // 4*6144*256*4 = 25165824
#define OFF_XC     100073472   // 4*256*8160*2 = 16711680  f16 [b][n][8160]
#define OFF_Y      116785152   // 8*4*256*256*4 = 8388608
// end ~125 MB

// ---------------- kNN (+ xyz -> padded f16 [b][n][32]) ----------------
__device__ __forceinline__ float dist3_nocontract(float ax, float ay, float az,
                                                  float bx, float by, float bz) {
#pragma clang fp contract(off)
    float dx = bx - ax, dy = by - ay, dz = bz - az;
    float s = dx * dx;
    s = s + dy * dy;
    s = s + dz * dz;
    return s;
}

__global__ __launch_bounds__(64) void knn_kernel(const float* __restrict__ x,
                                                 int* __restrict__ idx,
                                                 f16* __restrict__ xyz) {
    int pt = blockIdx.x;            // 0..1023
    int b = pt >> 8, n = pt & 255;
    int lane = threadIdx.x;

    float xp0 = x[pt * 3 + 0];
    float xp1 = x[pt * 3 + 1];
    float xp2 = x[pt * 3 + 2];

    if (lane < 32) {
        float v = (lane < 3) ? x[pt * 3 + lane] : 0.f;
        xyz[((long)b * NPTS + n) * 32 + lane] = (f16)v;
    }

    unsigned long long key[4];
#pragma unroll
    for (int u = 0; u < 4; ++u) {
        int j = lane + 64 * u;
        int gj = b * NPTS + j;
        float d = dist3_nocontract(xp0, xp1, xp2,
                                   x[gj * 3 + 0], x[gj * 3 + 1], x[gj * 3 + 2]);
        key[u] = ((unsigned long long)__float_as_uint(d) << 32) | (unsigned int)j;
    }

    for (int r = 0; r < KNN; ++r) {
        unsigned long long m = key[0];
        m = key[1] < m ? key[1] : m;
        m = key[2] < m ? key[2] : m;
        m = key[3] < m ? key[3] : m;
#pragma unroll
        for (int off = 32; off; off >>= 1) {
            unsigned long long o = __shfl_xor(m, off);
            m = o < m ? o : m;
        }
        if (lane == 0) idx[pt * KNN + r] = (int)(m & 0xffffffffu);
#pragma unroll
        for (int u = 0; u < 4; ++u)
            if (key[u] == m) key[u] = ~0ULL;
    }
}

// ---------------- consolidated weight prep (all 5 matrices, one dispatch) ----
// mode0: A[r][c] = r<Co ? w[r][c] : w[r-Co][K+c]-w[r-Co][c]  (w stride 2K)
// mode1: A[r][c] = w[r][c] (stride K). Zero-fill r>=M, c>=K. f16 output.
__global__ __launch_bounds__(256) void prep_all(
    const float* __restrict__ w0, const float* __restrict__ w1,
    const float* __restrict__ w2, const float* __restrict__ w3,
    const float* __restrict__ w4, char* __restrict__ ws)
{
    // cumulative block counts: 128, 512, 2048, 8192, 9216
    int bid = blockIdx.x;
    const float* w;
    int r, cbase = 0, M, Co, K, Kpad, mode;
    long offA;
    if (bid < 128)      { w = w0; r = bid;        M = 96;   Co = 48;   K = 3;    Kpad = 32;   mode = 0; offA = OFF_A0; }
    else if (bid < 512) { w = w1; r = bid - 128;  M = 384;  Co = 192;  K = 96;   Kpad = 96;   mode = 0; offA = OFF_A1; }
    else if (bid < 2048){ w = w2; r = bid - 512;  M = 1536; Co = 768;  K = 384;  Kpad = 384;  mode = 0; offA = OFF_A2; }
    else if (bid < 8192){ w = w3; r = bid - 2048; M = 6144; Co = 3072; K = 1536; Kpad = 1536; mode = 0; offA = OFF_A3; }
    else { int loc = bid - 8192; w = w4; r = loc >> 2; cbase = (loc & 3) * 2048;
           M = 256; Co = 0; K = 8160; Kpad = 8160; mode = 1; offA = OFF_A4; }

    int c0 = cbase + threadIdx.x * 8;
    if (c0 >= Kpad) return;
    f16* A = (f16*)(ws + offA);

    f16x8 hv;
#pragma unroll
    for (int j = 0; j < 8; ++j) {
        int c = c0 + j;
        float a = 0.f;
        if (c < K && r < M) {
            if (mode == 1) a = w[(long)r * K + c];
            else if (r < Co) a = w[(long)r * (2 * K) + c];
            else {
                long base = (long)(r - Co) * (2 * K);
                a = w[base + K + c] - w[base + c];
            }
        }
        hv[j] = (f16)a;
    }
    *(f16x8*)&A[(long)r * Kpad + c0] = hv;
}

// ---------------- f16 MFMA GEMM, split-K into private partial planes --------
// plane s: out[s*pstride + b*bsO + r*256 + n] = sum_{c in slice s} A[r][c]*F[b][n][c]
// Block 128x128, BK=32; 4 waves 2x2; wave 64x64 = 4x4 tiles of
// mfma_f32_16x16x32_f16 (same operand layout as m89-verified bf16 shape).
__global__ __launch_bounds__(256) void gemm_mfma(
    const f16* __restrict__ A, const f16* __restrict__ B,
    float* __restrict__ out, int M, int Kpad, int K,
    int ldF, long bsF, long bsO, int nsplit, long pstride)
{
    __shared__ u16 sA[128][40], sB[128][40];

    int bz = blockIdx.z;
    int b = bz / nsplit, slice = bz - b * nsplit;
    int kchunk = (((K + nsplit - 1) / nsplit) + 31) & ~31;
    int kstart = slice * kchunk;
    int kend = K < kstart + kchunk ? K : kstart + kchunk;

    const f16* pB = B + (long)b * bsF;
    float* Ob = out + (long)slice * pstride + (long)b * bsO;

    int m0 = blockIdx.x * 128, n0 = blockIdx.y * 128;
    int tid = threadIdx.x, lane = tid & 63, wid = tid >> 6;
    int wm = (wid >> 1) * 64, wn = (wid & 1) * 64;
    int lrow = lane & 15, quad = lane >> 4;

    int srow = tid >> 1;            // 0..127
    int sk = (tid & 1) * 16;        // 0,16

    const f16* gA = A + (long)(m0 + srow) * Kpad + sk;
    const f16* gB = pB + (long)(n0 + srow) * ldF + sk;

    f32x4 acc[4][4] = {};

    for (int kk = kstart; kk < kend; kk += 32) {
        f16x8 a0 = *(const f16x8*)(gA + kk);
        f16x8 a1 = *(const f16x8*)(gA + kk + 8);
        f16x8 b0 = *(const f16x8*)(gB + kk);
        f16x8 b1 = *(const f16x8*)(gB + kk + 8);

        __syncthreads();   // previous iteration's fragment reads complete

        *(f16x8*)&sA[srow][sk] = a0;
        *(f16x8*)&sA[srow][sk + 8] = a1;
        *(f16x8*)&sB[srow][sk] = b0;
        *(f16x8*)&sB[srow][sk + 8] = b1;

        __syncthreads();

        f16x8 fb[4];
#pragma unroll
        for (int nt = 0; nt < 4; ++nt)
            fb[nt] = *(const f16x8*)&sB[wn + nt * 16 + lrow][quad * 8];
#pragma unroll
        for (int mt = 0; mt < 4; ++mt) {
            f16x8 fa = *(const f16x8*)&sA[wm + mt * 16 + lrow][quad * 8];
#pragma unroll
            for (int nt = 0; nt < 4; ++nt)
                acc[mt][nt] = __builtin_amdgcn_mfma_f32_16x16x32_f16(fa, fb[nt], acc[mt][nt], 0, 0, 0);
        }
    }

    // epilogue: C/D layout col=lane&15, row=quad*4+reg  [m89-verified]
#pragma unroll
    for (int mt = 0; mt < 4; ++mt)
#pragma unroll
        for (int nt = 0; nt < 4; ++nt) {
            int C = n0 + wn + nt * 16 + lrow;
            int Rb = m0 + wm + mt * 16 + quad * 4;
#pragma unroll
            for (int r = 0; r < 4; ++r) {
                int R = Rb + r;
                if (R < M) Ob[(long)R * NPTS + C] = acc[mt][nt][r];
            }
        }
}

// ---------------- fused gather + stats + BN/lrelu + tp concat ---------------
// Sums nsplit partial planes when reading P/Q.
__global__ __launch_bounds__(256) void gather_finalize(
    const float* __restrict__ PQ, long pstride, int nsplit,
    const int* __restrict__ idx,
    const float* __restrict__ g, const float* __restrict__ beta,
    float* __restrict__ slice, int Co)
{
    __shared__ float p_sh[NB][NPTS];
    __shared__ float val_sh[NB][NPTS];
    __shared__ float red[8];
    int o = blockIdx.x;
    int b = threadIdx.x >> 6;
    int lane = threadIdx.x & 63;

    long ip0 = ((long)b * 2 * Co + o) * NPTS;
    long iq0 = ((long)b * 2 * Co + Co + o) * NPTS;

#pragma unroll
    for (int u = 0; u < 4; ++u) {
        int n = lane + 64 * u;
        float v = 0.f;
        for (int s = 0; s < nsplit; ++s) v += PQ[s * pstride + ip0 + n];
        p_sh[b][n] = v;
    }
    __syncthreads();

    float mx[4], mn[4];
    float s = 0.f, ss = 0.f;
#pragma unroll
    for (int u = 0; u < 4; ++u) {
        int n = lane + 64 * u;
        float q = 0.f;
        for (int sp = 0; sp < nsplit; ++sp) q += PQ[sp * pstride + iq0 + n];
        const int* ip = idx + ((long)b * NPTS + n) * KNN;
        float vmx = -__builtin_inff(), vmn = __builtin_inff();
#pragma unroll
        for (int k = 0; k < KNN; ++k) {
            float h = p_sh[b][ip[k]] + q;
            s += h;
            ss += h * h;
            vmx = fmaxf(vmx, h);
            vmn = fminf(vmn, h);
        }
        mx[u] = vmx;
        mn[u] = vmn;
    }
#pragma unroll
    for (int off = 32; off; off >>= 1) {
        s += __shfl_xor(s, off);
        ss += __shfl_xor(ss, off);
    }
    if (lane == 0) { red[b] = s; red[4 + b] = ss; }
    __syncthreads();

    float ts = (red[0] + red[1]) + (red[2] + red[3]);
    float tss = (red[4] + red[5]) + (red[6] + red[7]);
    const float cnt = (float)(NB * NPTS * KNN);
    float mean = ts / cnt;
    float var = tss / cnt - mean * mean;
    float sc = g[o] * (1.0f / sqrtf(var + EPSV));
    float tt = beta[o] - mean * sc;

#pragma unroll
    for (int u = 0; u < 4; ++u) {
        int n = lane + 64 * u;
        float v = (sc >= 0.f) ? mx[u] : mn[u];
        float z = sc * v + tt;
        val_sh[b][n] = z >= 0.f ? z : 0.2f * z;
    }
    __syncthreads();

#pragma unroll
    for (int u = 0; u < 4; ++u) {
        int n = lane + 64 * u;
        float tp = 0.5f * (val_sh[0][n] + val_sh[1][n]);
        slice[((long)b * 2 * Co + o) * NPTS + n] = val_sh[b][n];
        slice[((long)b * 2 * Co + Co + o) * NPTS + n] = tp;
    }
}

// ---------------- transpose [b][C][n] -> f16 [b][n][8160] at offc ----------
__global__ __launch_bounds__(256) void transpose_cn(
    const float* __restrict__ slice, f16* __restrict__ xc,
    int Ctot, int offc)
{
    __shared__ float t[32][33];
    int c0 = blockIdx.x * 32, n0 = blockIdx.y * 32, b = blockIdx.z;
    const float* S = slice + (long)b * Ctot * NPTS;
    int tid = threadIdx.x;
    int r = tid >> 3, s4 = (tid & 7) * 4;

    f32x4 v = *(const f32x4*)&S[(long)(c0 + r) * NPTS + n0 + s4];
    t[r][s4 + 0] = v[0];
    t[r][s4 + 1] = v[1];
    t[r][s4 + 2] = v[2];
    t[r][s4 + 3] = v[3];
    __syncthreads();

    long base = ((long)b * NPTS + n0 + r) * 8160 + offc + c0 + s4;
    typedef __attribute__((ext_vector_type(4))) _Float16 f16x4;
    f16x4 hv;
#pragma unroll
    for (int j = 0; j < 4; ++j) hv[j] = (f16)t[s4 + j][r];
    *(f16x4*)&xc[base] = hv;
}

// ---------------- final BN + lrelu -> fp32 out (sums 8 partial y planes) ----
__global__ __launch_bounds__(256) void final_bn(const float* __restrict__ y,
                                                const float* __restrict__ g4,
                                                const float* __restrict__ b4,
                                                float* __restrict__ out) {
    __shared__ float red[8];
    int o = blockIdx.x;
    int tid = threadIdx.x;
    int lane = tid & 63, w = tid >> 6;

    float v[4];
    float s = 0.f, ss = 0.f;
#pragma unroll
    for (int b = 0; b < 4; ++b) {
        float acc = 0.f;
#pragma unroll
        for (int sp = 0; sp < 8; ++sp)
            acc += y[sp * 262144 + b * 65536 + o * 256 + tid];
        v[b] = acc;
        s += acc;
        ss += acc * acc;
    }
#pragma unroll
    for (int off = 32; off; off >>= 1) {
        s += __shfl_xor(s, off);
        ss += __shfl_xor(ss, off);
    }
    if (lane == 0) { red[w] = s; red[4 + w] = ss; }
    __syncthreads();
    s = (red[0] + red[1]) + (red[2] + red[3]);
    ss = (red[4] + red[5]) + (red[6] + red[7]);
    float mean = s / 1024.f;
    float var = ss / 1024.f - mean * mean;
    float sc = g4[o] * (1.0f / sqrtf(var + EPSV));
    float tt = b4[o] - mean * sc;
#pragma unroll
    for (int b = 0; b < 4; ++b) {
        float z = sc * v[b] + tt;
        z = z >= 0.f ? z : 0.2f * z;
        out[(long)b * 65536 + o * 256 + tid] = z;
    }
}

// ---------------- launch ----------------
extern "C" void kernel_launch(void* const* d_in, const int* in_sizes, int n_in,
                              void* d_out, int out_size, void* d_ws, size_t ws_size,
                              hipStream_t stream) {
    const float* x = (const float*)d_in[0];
    const float* wl[4];
    const float* gl[4];
    const float* bl[4];
    for (int i = 0; i < 4; ++i) {
        wl[i] = (const float*)d_in[1 + 3 * i];
        gl[i] = (const float*)d_in[2 + 3 * i];
        bl[i] = (const float*)d_in[3 + 3 * i];
    }
    const float* w4 = (const float*)d_in[13];
    const float* g4 = (const float*)d_in[14];
    const float* b4 = (const float*)d_in[15];

    char* ws = (char*)d_ws;
    int* idx = (int*)(ws + OFF_IDX);
    f16* xyz = (f16*)(ws + OFF_XYZ);
    float* PQ = (float*)(ws + OFF_PQ);
    float* slice = (float*)(ws + OFF_SLICE);
    f16* xc = (f16*)(ws + OFF_XC);
    float* y = (float*)(ws + OFF_Y);

    knn_kernel<<<dim3(NB * NPTS), dim3(64), 0, stream>>>(x, idx, xyz);
    prep_all<<<dim3(9216), dim3(256), 0, stream>>>(wl[0], wl[1], wl[2], wl[3], w4, ws);

    const int Kp[4] = {32, 96, 384, 1536};     // padded K (multiples of 32)
    const int Co[4] = {48, 192, 768, 3072};
    const int offc[4] = {0, 96, 480, 2016};
    const int inoff[4] = {0, 0, 96, 480};
    const int nsp[4] = {1, 3, 4, 2};
    const long aoff[4] = {OFF_A0, OFF_A1, OFF_A2, OFF_A3};

    for (int i = 0; i < 4; ++i) {
        int M = 2 * Co[i];
        int Mpad = (M + 127) & ~127;
        const f16* A = (const f16*)(ws + aoff[i]);

        const f16* Bp;
        int ldF;
        long bsF;
        if (i == 0) { Bp = xyz; ldF = 32; bsF = (long)NPTS * 32; }
        else { Bp = xc + inoff[i]; ldF = 8160; bsF = (long)NPTS * 8160; }

        long pstride = (long)NB * M * NPTS;   // one partial plane
        gemm_mfma<<<dim3(Mpad / 128, NPTS / 128, NB * nsp[i]), dim3(256), 0, stream>>>(
            A, Bp, PQ, M, Kp[i], Kp[i], ldF, bsF, (long)M * NPTS, nsp[i], pstride);

        gather_finalize<<<dim3(Co[i]), dim3(256), 0, stream>>>(
            PQ, pstride, nsp[i], idx, gl[i], bl[i], slice, Co[i]);
        transpose_cn<<<dim3(M / 32, NPTS / 32, NB), dim3(256), 0, stream>>>(
            slice, xc, M, offc[i]);
    }

    // final projection: split-K=8 into 8 private y planes, summed in final_bn
    gemm_mfma<<<dim3(2, 2, NB * 8), dim3(256), 0, stream>>>(
        (const f16*)(ws + OFF_A4), xc, y, 256, 8160, 8160, 8160,
        (long)NPTS * 8160, (long)256 * NPTS, 8, (long)NB * 256 * NPTS);
    final_bn<<<dim3(256), dim3(256), 0, stream>>>(y, g4, b4, (float*)d_out);
}